// Round 6
// baseline (103.302 us; speedup 1.0000x reference)
//
#include <hip/hip_runtime.h>
#include <hip/hip_bf16.h>

// Problem sizes (fixed by reference)
#define N_NODES   100000
#define N_EDGES   640000
#define NUM_GRAPHS 128
#define NUM_FEAT  128
#define HIDDEN    16
#define NUM_CLS   10

// Bucket sort params
#define NBLK   256                 // edge-chunk blocks in bcount/place
#define EPB    (N_EDGES / NBLK)    // 2500 edges per block (exact)
#define NBUCK  256                 // dst >> 9 -> 196 used buckets
#define BSHIFT 9
#define BNODES 512                 // nodes per bucket

// ---------------- K1: (mm1 role) y = x @ W1  ||  (bcount role) bucket hist -----
#define MM1_ROWS 64
__global__ __launch_bounds__(256) void k_mm1_bcount(const float* __restrict__ x,
                                                    const float* __restrict__ W1,
                                                    float* __restrict__ y,
                                                    const int* __restrict__ ei,
                                                    int* __restrict__ cnt,
                                                    int N, int gridMM1) {
    __shared__ float sx[MM1_ROWS][132];   // also aliased as bcount's histogram
    __shared__ float sw[NUM_FEAT * HIDDEN];
    const int t = threadIdx.x;

    if (blockIdx.x >= gridMM1) {
        // ---- bucket histogram role (LDS atomics only) ----
        int* h = (int*)&sx[0][0];
        const int b = blockIdx.x - gridMM1;
        h[t] = 0;
        __syncthreads();
        const int e0 = b * EPB, e1 = e0 + EPB;
        for (int e = e0 + t; e < e1; e += 256)
            atomicAdd(&h[ei[N_EDGES + e] >> BSHIFT], 1);
        __syncthreads();
        cnt[b * NBUCK + t] = h[t];   // block-major: coalesced for k_place
        return;
    }

    // ---- mm1 role ----
    const int rowbase = blockIdx.x * MM1_ROWS;
    const int nrows = min(MM1_ROWS, N - rowbase);

    for (int i = t; i < NUM_FEAT * HIDDEN; i += 256) sw[i] = W1[i];

    for (int i = t; i < nrows * 32; i += 256) {
        int r = i >> 5, q = i & 31;
        float4 v = ((const float4*)(x + (size_t)(rowbase + r) * NUM_FEAT))[q];
        *(float4*)&sx[r][q * 4] = v;
    }
    __syncthreads();

    const int r  = t >> 2;
    const int c0 = (t & 3) * 4;
    if (r < nrows) {
        float4 o = {0.f, 0.f, 0.f, 0.f};
        #pragma unroll 4
        for (int k4 = 0; k4 < 32; ++k4) {
            float4 xv = *(const float4*)&sx[r][k4 * 4];
            const float* wb = &sw[(k4 * 4) * HIDDEN + c0];
            float4 w0 = *(const float4*)(wb);
            float4 w1 = *(const float4*)(wb + HIDDEN);
            float4 w2 = *(const float4*)(wb + 2 * HIDDEN);
            float4 w3 = *(const float4*)(wb + 3 * HIDDEN);
            o.x += xv.x * w0.x + xv.y * w1.x + xv.z * w2.x + xv.w * w3.x;
            o.y += xv.x * w0.y + xv.y * w1.y + xv.z * w2.y + xv.w * w3.y;
            o.z += xv.x * w0.z + xv.y * w1.z + xv.z * w2.z + xv.w * w3.z;
            o.w += xv.x * w0.w + xv.y * w1.w + xv.z * w2.w + xv.w * w3.w;
        }
        ((float4*)(y + (size_t)(rowbase + r) * HIDDEN))[t & 3] = o;
    }
}

// ---------------- K2: place edges (self-derived cursors; no bscan kernel) ------
// Block b, thread t owns bucket t: scans cnt column t (coalesced across lanes)
// for bucket total + own-block prefix; LDS-scans totals for bucket bases.
// Block 0 publishes bases[] and zeroes sums/counts/done.
__global__ __launch_bounds__(256) void k_place(const int* __restrict__ ei,
                                               const int* __restrict__ cnt,
                                               int* __restrict__ bases,
                                               unsigned* __restrict__ packed,
                                               int* __restrict__ zarea, int nz) {
    __shared__ int s[NBUCK];
    __shared__ int cur[NBUCK];
    const int t = threadIdx.x, b = blockIdx.x;

    int tot = 0, own = 0;
    for (int i = 0; i < NBLK; ++i) {
        int v = cnt[i * NBUCK + t];      // lanes read consecutive ints: coalesced
        tot += v;
        own += (i < b) ? v : 0;
    }
    s[t] = tot;
    __syncthreads();
    for (int off = 1; off < NBUCK; off <<= 1) {
        int add = (t >= off) ? s[t - off] : 0;
        __syncthreads();
        s[t] += add;
        __syncthreads();
    }
    const int base = s[t] - tot;         // exclusive bucket base
    cur[t] = base + own;
    if (b == 0) {
        bases[t] = base;
        if (t == NBUCK - 1) bases[NBUCK] = N_EDGES;
        for (int i = t; i < nz; i += 256) zarea[i] = 0;   // sums, counts, done
    }
    __syncthreads();

    const int e0 = b * EPB, e1 = e0 + EPB;
    for (int e = e0 + t; e < e1; e += 256) {
        int srcv = ei[e];
        int dstv = ei[N_EDGES + e];
        int k = dstv >> BSHIFT;
        int slot = atomicAdd(&cur[k], 1);                 // LDS atomic
        packed[slot] = ((unsigned)(dstv & (BNODES - 1)) << 17) | (unsigned)srcv;
    }
}

// ---------------- K3: per-bucket: row[] + srcidx[] (LDS hist/scan/cursor) ------
__global__ __launch_bounds__(256) void k_build(const unsigned* __restrict__ packed,
                                               const int* __restrict__ bases,
                                               int* __restrict__ row,
                                               int* __restrict__ srcidx) {
    __shared__ int h[BNODES];
    __shared__ int ps[256];
    __shared__ int e2[BNODES];
    __shared__ int cur[BNODES];
    const int k = blockIdx.x, t = threadIdx.x;
    const int s0 = bases[k];
    const int s1 = bases[k + 1];

    h[t] = 0; h[t + 256] = 0;
    __syncthreads();
    for (int i = s0 + t; i < s1; i += 256)
        atomicAdd(&h[packed[i] >> 17], 1);
    __syncthreads();
    int pv = h[2 * t] + h[2 * t + 1];
    ps[t] = pv;
    __syncthreads();
    for (int off = 1; off < 256; off <<= 1) {
        int add = (t >= off) ? ps[t - off] : 0;
        __syncthreads();
        ps[t] += add;
        __syncthreads();
    }
    int ex = ps[t] - pv;
    e2[2 * t] = ex;               e2[2 * t + 1] = ex + h[2 * t];
    cur[2 * t] = ex;              cur[2 * t + 1] = ex + h[2 * t];
    __syncthreads();
    #pragma unroll
    for (int jj = 0; jj < 2; ++jj) {
        int j = t + jj * 256;
        int node = (k << BSHIFT) + j;
        if (node <= N_NODES) row[node] = s0 + e2[j];   // row[N] sentinel = E
    }
    __syncthreads();
    for (int i = s0 + t; i < s1; i += 256) {
        unsigned p = packed[i];
        int dl = p >> 17;
        int slot = atomicAdd(&cur[dl], 1);             // LDS atomic
        srcidx[s0 + slot] = (int)(p & 0x1FFFFu);
    }
}

// ---- K4 g1f: B[n] = relu(A[n] + sum A[src] + b1) @ W2  (gather + GIN fused) ---
__global__ __launch_bounds__(256) void k_g1f(const int* __restrict__ row,
                                             const int* __restrict__ srcidx,
                                             const float* __restrict__ A,
                                             const float* __restrict__ bias,
                                             const float* __restrict__ W2,
                                             float* __restrict__ B, int N) {
    __shared__ float sw[HIDDEN * HIDDEN];
    const int t = threadIdx.x;
    if (t < HIDDEN * HIDDEN) sw[t] = W2[t];
    __syncthreads();
    const int n = blockIdx.x * 64 + (t >> 2);
    const int p = t & 3;
    if (n >= N) return;
    const int r0 = row[n];
    const int d  = row[n + 1] - r0;
    float4 acc = ((const float4*)(A + (size_t)n * HIDDEN))[p];
    for (int i = 0; i < d; ++i) {
        int s = srcidx[r0 + i];
        float4 v = ((const float4*)(A + (size_t)s * HIDDEN))[p];
        acc.x += v.x; acc.y += v.y; acc.z += v.z; acc.w += v.w;
    }
    const float4 bv = ((const float4*)bias)[p];
    acc.x = fmaxf(acc.x + bv.x, 0.f);
    acc.y = fmaxf(acc.y + bv.y, 0.f);
    acc.z = fmaxf(acc.z + bv.z, 0.f);
    acc.w = fmaxf(acc.w + bv.w, 0.f);
    // h(16) @ W2 -> this thread's 4 output cols; exchange h quads via shfl
    const int lane = t & 63;
    const int qbase = lane & ~3;
    const int c0 = p * 4;
    float4 o = {0.f, 0.f, 0.f, 0.f};
    #pragma unroll
    for (int q = 0; q < 4; ++q) {
        float hx = __shfl(acc.x, qbase + q, 64);
        float hy = __shfl(acc.y, qbase + q, 64);
        float hz = __shfl(acc.z, qbase + q, 64);
        float hw = __shfl(acc.w, qbase + q, 64);
        const float* wb = &sw[(q * 4) * HIDDEN + c0];
        float4 w0 = *(const float4*)(wb);
        float4 w1 = *(const float4*)(wb + HIDDEN);
        float4 w2 = *(const float4*)(wb + 2 * HIDDEN);
        float4 w3 = *(const float4*)(wb + 3 * HIDDEN);
        o.x += hx * w0.x + hy * w1.x + hz * w2.x + hw * w3.x;
        o.y += hx * w0.y + hy * w1.y + hz * w2.y + hw * w3.y;
        o.z += hx * w0.z + hy * w1.z + hz * w2.z + hw * w3.z;
        o.w += hx * w0.w + hy * w1.w + hz * w2.w + hw * w3.w;
    }
    ((float4*)(B + (size_t)n * HIDDEN))[p] = o;
}

// ---- K5 g2p: pool(relu(B[n] + sum B[src] + b2)) -> sums/counts; last block FC -
#define POOL_BLOCKS 1024
__global__ __launch_bounds__(256) void k_g2p(const int* __restrict__ row,
                                             const int* __restrict__ srcidx,
                                             const float* __restrict__ B,
                                             const float* __restrict__ bias,
                                             const int* __restrict__ batch,
                                             float* __restrict__ sums,
                                             float* __restrict__ counts,
                                             unsigned* __restrict__ done,
                                             const float* __restrict__ Wfc,
                                             const float* __restrict__ bfc,
                                             float* __restrict__ out,
                                             int N, int chunk) {
    __shared__ float ssum[NUM_GRAPHS * HIDDEN];
    __shared__ float scnt[NUM_GRAPHS];
    __shared__ unsigned sdone;
    const int t = threadIdx.x;
    for (int i = t; i < NUM_GRAPHS * HIDDEN; i += 256) ssum[i] = 0.f;
    if (t < NUM_GRAPHS) scnt[t] = 0.f;
    __syncthreads();

    const int n0 = blockIdx.x * chunk;
    const int n1 = min(n0 + chunk, N);
    const int lane = t & 63;
    const int p = t & 3;
    const float4 bv = ((const float4*)bias)[p];

    for (int nb = n0; nb < n1; nb += 64) {
        int n = nb + (t >> 2);
        bool active = (n < n1);
        int nc = active ? n : (n1 - 1);
        int g = batch[nc];
        float4 h = {0.f, 0.f, 0.f, 0.f};
        if (active) {
            int r0 = row[n];
            int d  = row[n + 1] - r0;
            h = ((const float4*)(B + (size_t)n * HIDDEN))[p];
            for (int i = 0; i < d; ++i) {
                int s = srcidx[r0 + i];
                float4 v = ((const float4*)(B + (size_t)s * HIDDEN))[p];
                h.x += v.x; h.y += v.y; h.z += v.z; h.w += v.w;
            }
            h.x = fmaxf(h.x + bv.x, 0.f);
            h.y = fmaxf(h.y + bv.y, 0.f);
            h.z = fmaxf(h.z + bv.z, 0.f);
            h.w = fmaxf(h.w + bv.w, 0.f);
        }
        int gf = __builtin_amdgcn_readfirstlane(g);
        bool uniform = (__ballot(g == gf) == ~0ull);
        if (uniform) {
            #pragma unroll
            for (int m = 4; m <= 32; m <<= 1) {
                h.x += __shfl_xor(h.x, m, 64);
                h.y += __shfl_xor(h.y, m, 64);
                h.z += __shfl_xor(h.z, m, 64);
                h.w += __shfl_xor(h.w, m, 64);
            }
            if (lane < 4) {
                float* sp = &ssum[gf * HIDDEN + p * 4];
                atomicAdd(sp + 0, h.x);
                atomicAdd(sp + 1, h.y);
                atomicAdd(sp + 2, h.z);
                atomicAdd(sp + 3, h.w);
            }
            if (lane == 0) {
                int wfirst = nb + ((t >> 6) << 4);
                int cnt = min(16, n1 - wfirst);
                if (cnt > 0) atomicAdd(&scnt[gf], (float)cnt);
            }
        } else if (active) {
            float* sp = &ssum[g * HIDDEN + p * 4];
            atomicAdd(sp + 0, h.x);
            atomicAdd(sp + 1, h.y);
            atomicAdd(sp + 2, h.z);
            atomicAdd(sp + 3, h.w);
            if (p == 0) atomicAdd(&scnt[g], 1.f);
        }
    }
    __syncthreads();
    // flush block partials (device-scope atomics; memory-side on gfx950)
    for (int i = t; i < NUM_GRAPHS * HIDDEN; i += 256) {
        float v = ssum[i];
        if (v != 0.f) atomicAdd(&sums[i], v);
    }
    if (t < NUM_GRAPHS) {
        float v = scnt[t];
        if (v != 0.f) atomicAdd(&counts[t], v);
    }
    __syncthreads();   // drains this block's vmem (compiler emits vmcnt(0))
    if (t == 0) sdone = atomicAdd(done, 1u);
    __syncthreads();
    if (sdone == POOL_BLOCKS - 1) {
        // last block: all other blocks' flushes complete -> FC head
        __threadfence();
        for (int i = t; i < NUM_GRAPHS * NUM_CLS; i += 256) {
            int g = i / NUM_CLS, c = i % NUM_CLS;
            float inv = 1.0f / fmaxf(counts[g], 1.0f);
            float acc = bfc[c];
            #pragma unroll
            for (int kk = 0; kk < HIDDEN; ++kk)
                acc += (sums[g * HIDDEN + kk] * inv) * Wfc[kk * NUM_CLS + c];
            out[i] = acc;
        }
    }
}

extern "C" void kernel_launch(void* const* d_in, const int* in_sizes, int n_in,
                              void* d_out, int out_size, void* d_ws, size_t ws_size,
                              hipStream_t stream) {
    const float* x    = (const float*)d_in[0];
    const int*   ei   = (const int*)d_in[1];   // [2, E] (src row then dst row)
    const int*   batch= (const int*)d_in[2];
    const float* W1   = (const float*)d_in[3];
    const float* b1   = (const float*)d_in[4];
    const float* W2   = (const float*)d_in[5];
    const float* b2   = (const float*)d_in[6];
    const float* Wfc  = (const float*)d_in[7];
    const float* bfc  = (const float*)d_in[8];
    float* out = (float*)d_out;

    const size_t NB = (size_t)N_NODES * HIDDEN * sizeof(float);   // 6.4 MB
    char* ws = (char*)d_ws;
    size_t off = 0;
    float* A      = (float*)(ws + off); off += NB;
    float* B      = (float*)(ws + off); off += NB;
    // zero-area: sums | counts | done (contiguous, zeroed by k_place block 0)
    float*    sums   = (float*)(ws + off); off += (size_t)NUM_GRAPHS * HIDDEN * sizeof(float);
    float*    counts = (float*)(ws + off); off += (size_t)NUM_GRAPHS * sizeof(float);
    unsigned* done   = (unsigned*)(ws + off); off += 16;
    const int nz = NUM_GRAPHS * HIDDEN + NUM_GRAPHS + 1;
    int* row    = (int*)(ws + off); off += (size_t)(N_NODES + 4) * sizeof(int);
    int* cnt    = (int*)(ws + off); off += (size_t)NBLK * NBUCK * sizeof(int);
    int* bases  = (int*)(ws + off); off += (size_t)(NBUCK + 1) * sizeof(int);
    off = (off + 15) & ~(size_t)15;
    int* srcidx = (int*)(ws + off); off += (size_t)N_EDGES * sizeof(int);
    // packed edge words alias B: place writes / build reads them strictly before
    // k_g1f (stream-ordered) overwrites B.
    unsigned* packed = (unsigned*)B;

    const int gridMM1 = (N_NODES + MM1_ROWS - 1) / MM1_ROWS;
    const int gridG1  = (N_NODES + 63) / 64;
    const int poolChunk = (N_NODES + POOL_BLOCKS - 1) / POOL_BLOCKS;

    // K1: mm1 || bucket histogram (independent work, one launch)
    k_mm1_bcount<<<gridMM1 + NBLK, 256, 0, stream>>>(x, W1, A, ei, cnt,
                                                     N_NODES, gridMM1);
    // K2: place (self-scan cursors; publishes bases; zeroes sums/counts/done)
    k_place<<<NBLK, 256, 0, stream>>>(ei, cnt, bases, packed, (int*)sums, nz);
    // K3: per-bucket CSR finalize
    k_build<<<NBUCK, 256, 0, stream>>>(packed, bases, row, srcidx);

    // K4: layer 1+2 fused: B = relu(A + gather(A) + b1) @ W2
    k_g1f<<<gridG1, 256, 0, stream>>>(row, srcidx, A, b1, W2, B, N_NODES);

    // K5: pool(relu(B + gather(B) + b2)) -> sums/counts ; last block does FC
    k_g2p<<<POOL_BLOCKS, 256, 0, stream>>>(row, srcidx, B, b2, batch, sums, counts,
                                           done, Wfc, bfc, out, N_NODES, poolChunk);
}

// Round 7
// 96.295 us; speedup vs baseline: 1.0728x; 1.0728x over previous
//
#include <hip/hip_runtime.h>
#include <hip/hip_bf16.h>

// Problem sizes (fixed by reference)
#define N_NODES   100000
#define N_EDGES   640000
#define NUM_GRAPHS 128
#define NUM_FEAT  128
#define HIDDEN    16
#define NUM_CLS   10

// Bucket sort params
#define NBLK   256                 // edge-chunk blocks in place
#define EPB    (N_EDGES / NBLK)    // 2500 edges per block (exact)
#define NBUCK  256                 // dst >> 9 -> 196 used buckets
#define BSHIFT 9
#define BNODES 512                 // nodes per bucket
#define CAP    4096                // fixed region per bucket (max bucket ~3477)

// ---------------- K1: y = x @ W1 ; one extra block zeroes gcur/sums/counts/done
#define MM1_ROWS 64
__global__ __launch_bounds__(256) void k_mm1z(const float* __restrict__ x,
                                              const float* __restrict__ W1,
                                              float* __restrict__ y,
                                              int* __restrict__ zarea, int nz,
                                              int N, int gridMM1) {
    const int t = threadIdx.x;
    if (blockIdx.x >= gridMM1) {
        for (int i = t; i < nz; i += 256) zarea[i] = 0;
        return;
    }
    __shared__ float sx[MM1_ROWS][132];
    __shared__ float sw[NUM_FEAT * HIDDEN];
    const int rowbase = blockIdx.x * MM1_ROWS;
    const int nrows = min(MM1_ROWS, N - rowbase);

    for (int i = t; i < NUM_FEAT * HIDDEN; i += 256) sw[i] = W1[i];

    for (int i = t; i < nrows * 32; i += 256) {
        int r = i >> 5, q = i & 31;
        float4 v = ((const float4*)(x + (size_t)(rowbase + r) * NUM_FEAT))[q];
        *(float4*)&sx[r][q * 4] = v;
    }
    __syncthreads();

    const int r  = t >> 2;
    const int c0 = (t & 3) * 4;
    if (r < nrows) {
        float4 o = {0.f, 0.f, 0.f, 0.f};
        #pragma unroll 4
        for (int k4 = 0; k4 < 32; ++k4) {
            float4 xv = *(const float4*)&sx[r][k4 * 4];
            const float* wb = &sw[(k4 * 4) * HIDDEN + c0];
            float4 w0 = *(const float4*)(wb);
            float4 w1 = *(const float4*)(wb + HIDDEN);
            float4 w2 = *(const float4*)(wb + 2 * HIDDEN);
            float4 w3 = *(const float4*)(wb + 3 * HIDDEN);
            o.x += xv.x * w0.x + xv.y * w1.x + xv.z * w2.x + xv.w * w3.x;
            o.y += xv.x * w0.y + xv.y * w1.y + xv.z * w2.y + xv.w * w3.y;
            o.z += xv.x * w0.z + xv.y * w1.z + xv.z * w2.z + xv.w * w3.z;
            o.w += xv.x * w0.w + xv.y * w1.w + xv.z * w2.w + xv.w * w3.w;
        }
        ((float4*)(y + (size_t)(rowbase + r) * HIDDEN))[t & 3] = o;
    }
}

// ---------------- K2: hist + capacity-alloc + place (no cross-block scan) ------
// Block b: LDS-hist its 2500-edge chunk; thread t allocates a sub-region of
// bucket t's fixed CAP region via ONE global atomicAdd; place via LDS cursors.
__global__ __launch_bounds__(256) void k_place2(const int* __restrict__ ei,
                                                int* __restrict__ gcur,
                                                unsigned* __restrict__ packed) {
    __shared__ int hist[NBUCK];
    __shared__ int cur[NBUCK];
    const int t = threadIdx.x, b = blockIdx.x;
    hist[t] = 0;
    __syncthreads();
    const int e0 = b * EPB, e1 = e0 + EPB;
    for (int e = e0 + t; e < e1; e += 256)
        atomicAdd(&hist[ei[N_EDGES + e] >> BSHIFT], 1);   // LDS atomic
    __syncthreads();
    int h = hist[t];
    int base = 0;
    if (h > 0) base = atomicAdd(&gcur[t], h);             // 1 global atomic/bucket
    cur[t] = t * CAP + base;
    __syncthreads();
    for (int e = e0 + t; e < e1; e += 256) {
        int srcv = ei[e];
        int dstv = ei[N_EDGES + e];
        int k = dstv >> BSHIFT;
        int slot = atomicAdd(&cur[k], 1);                 // LDS atomic
        packed[slot] = ((unsigned)(dstv & (BNODES - 1)) << 17) | (unsigned)srcv;
    }
}

// ---------------- K3: per-bucket: row[]/deg[] + srcidx[] (gapped regions) ------
__global__ __launch_bounds__(256) void k_build2(const unsigned* __restrict__ packed,
                                                const int* __restrict__ gcur,
                                                int* __restrict__ row,
                                                int* __restrict__ deg,
                                                int* __restrict__ srcidx) {
    __shared__ int h[BNODES];
    __shared__ int ps[256];
    __shared__ int e2[BNODES];
    __shared__ int cur[BNODES];
    const int k = blockIdx.x, t = threadIdx.x;
    const int s0 = k * CAP;
    const int s1 = s0 + gcur[k];

    h[t] = 0; h[t + 256] = 0;
    __syncthreads();
    for (int i = s0 + t; i < s1; i += 256)
        atomicAdd(&h[packed[i] >> 17], 1);
    __syncthreads();
    int pv = h[2 * t] + h[2 * t + 1];
    ps[t] = pv;
    __syncthreads();
    for (int off = 1; off < 256; off <<= 1) {
        int add = (t >= off) ? ps[t - off] : 0;
        __syncthreads();
        ps[t] += add;
        __syncthreads();
    }
    int ex = ps[t] - pv;
    e2[2 * t] = ex;               e2[2 * t + 1] = ex + h[2 * t];
    cur[2 * t] = ex;              cur[2 * t + 1] = ex + h[2 * t];
    __syncthreads();
    #pragma unroll
    for (int jj = 0; jj < 2; ++jj) {
        int j = t + jj * 256;
        int node = (k << BSHIFT) + j;
        if (node < N_NODES) {
            row[node] = s0 + e2[j];
            deg[node] = h[j];
        }
    }
    __syncthreads();
    for (int i = s0 + t; i < s1; i += 256) {
        unsigned p = packed[i];
        int dl = p >> 17;
        int slot = atomicAdd(&cur[dl], 1);             // LDS atomic
        srcidx[s0 + slot] = (int)(p & 0x1FFFFu);
    }
}

// ---- K4 g1f: B[n] = relu(A[n] + sum A[src] + b1) @ W2  (gather + GIN fused) ---
__global__ __launch_bounds__(256) void k_g1f(const int* __restrict__ row,
                                             const int* __restrict__ deg,
                                             const int* __restrict__ srcidx,
                                             const float* __restrict__ A,
                                             const float* __restrict__ bias,
                                             const float* __restrict__ W2,
                                             float* __restrict__ B, int N) {
    __shared__ float sw[HIDDEN * HIDDEN];
    const int t = threadIdx.x;
    if (t < HIDDEN * HIDDEN) sw[t] = W2[t];
    __syncthreads();
    const int n = blockIdx.x * 64 + (t >> 2);
    const int p = t & 3;
    if (n >= N) return;
    const int r0 = row[n];
    const int d  = deg[n];
    float4 acc = ((const float4*)(A + (size_t)n * HIDDEN))[p];
    for (int i = 0; i < d; ++i) {
        int s = srcidx[r0 + i];
        float4 v = ((const float4*)(A + (size_t)s * HIDDEN))[p];
        acc.x += v.x; acc.y += v.y; acc.z += v.z; acc.w += v.w;
    }
    const float4 bv = ((const float4*)bias)[p];
    acc.x = fmaxf(acc.x + bv.x, 0.f);
    acc.y = fmaxf(acc.y + bv.y, 0.f);
    acc.z = fmaxf(acc.z + bv.z, 0.f);
    acc.w = fmaxf(acc.w + bv.w, 0.f);
    // h(16) @ W2 -> this thread's 4 output cols; exchange h quads via shfl
    const int lane = t & 63;
    const int qbase = lane & ~3;
    const int c0 = p * 4;
    float4 o = {0.f, 0.f, 0.f, 0.f};
    #pragma unroll
    for (int q = 0; q < 4; ++q) {
        float hx = __shfl(acc.x, qbase + q, 64);
        float hy = __shfl(acc.y, qbase + q, 64);
        float hz = __shfl(acc.z, qbase + q, 64);
        float hw = __shfl(acc.w, qbase + q, 64);
        const float* wb = &sw[(q * 4) * HIDDEN + c0];
        float4 w0 = *(const float4*)(wb);
        float4 w1 = *(const float4*)(wb + HIDDEN);
        float4 w2 = *(const float4*)(wb + 2 * HIDDEN);
        float4 w3 = *(const float4*)(wb + 3 * HIDDEN);
        o.x += hx * w0.x + hy * w1.x + hz * w2.x + hw * w3.x;
        o.y += hx * w0.y + hy * w1.y + hz * w2.y + hw * w3.y;
        o.z += hx * w0.z + hy * w1.z + hz * w2.z + hw * w3.z;
        o.w += hx * w0.w + hy * w1.w + hz * w2.w + hw * w3.w;
    }
    ((float4*)(B + (size_t)n * HIDDEN))[p] = o;
}

// ---- K5 g2p: pool(relu(B[n] + sum B[src] + b2)) -> sums/counts; last block FC -
#define POOL_BLOCKS 1024
__global__ __launch_bounds__(256) void k_g2p(const int* __restrict__ row,
                                             const int* __restrict__ deg,
                                             const int* __restrict__ srcidx,
                                             const float* __restrict__ B,
                                             const float* __restrict__ bias,
                                             const int* __restrict__ batch,
                                             float* __restrict__ sums,
                                             float* __restrict__ counts,
                                             unsigned* __restrict__ done,
                                             const float* __restrict__ Wfc,
                                             const float* __restrict__ bfc,
                                             float* __restrict__ out,
                                             int N, int chunk) {
    __shared__ float ssum[NUM_GRAPHS * HIDDEN];
    __shared__ float scnt[NUM_GRAPHS];
    __shared__ unsigned sdone;
    const int t = threadIdx.x;
    for (int i = t; i < NUM_GRAPHS * HIDDEN; i += 256) ssum[i] = 0.f;
    if (t < NUM_GRAPHS) scnt[t] = 0.f;
    __syncthreads();

    const int n0 = blockIdx.x * chunk;
    const int n1 = min(n0 + chunk, N);
    const int lane = t & 63;
    const int p = t & 3;
    const float4 bv = ((const float4*)bias)[p];

    for (int nb = n0; nb < n1; nb += 64) {
        int n = nb + (t >> 2);
        bool active = (n < n1);
        int nc = active ? n : (n1 - 1);
        int g = batch[nc];
        float4 h = {0.f, 0.f, 0.f, 0.f};
        if (active) {
            int r0 = row[n];
            int d  = deg[n];
            h = ((const float4*)(B + (size_t)n * HIDDEN))[p];
            for (int i = 0; i < d; ++i) {
                int s = srcidx[r0 + i];
                float4 v = ((const float4*)(B + (size_t)s * HIDDEN))[p];
                h.x += v.x; h.y += v.y; h.z += v.z; h.w += v.w;
            }
            h.x = fmaxf(h.x + bv.x, 0.f);
            h.y = fmaxf(h.y + bv.y, 0.f);
            h.z = fmaxf(h.z + bv.z, 0.f);
            h.w = fmaxf(h.w + bv.w, 0.f);
        }
        int gf = __builtin_amdgcn_readfirstlane(g);
        bool uniform = (__ballot(g == gf) == ~0ull);
        if (uniform) {
            #pragma unroll
            for (int m = 4; m <= 32; m <<= 1) {
                h.x += __shfl_xor(h.x, m, 64);
                h.y += __shfl_xor(h.y, m, 64);
                h.z += __shfl_xor(h.z, m, 64);
                h.w += __shfl_xor(h.w, m, 64);
            }
            if (lane < 4) {
                float* sp = &ssum[gf * HIDDEN + p * 4];
                atomicAdd(sp + 0, h.x);
                atomicAdd(sp + 1, h.y);
                atomicAdd(sp + 2, h.z);
                atomicAdd(sp + 3, h.w);
            }
            if (lane == 0) {
                int wfirst = nb + ((t >> 6) << 4);
                int cnt = min(16, n1 - wfirst);
                if (cnt > 0) atomicAdd(&scnt[gf], (float)cnt);
            }
        } else if (active) {
            float* sp = &ssum[g * HIDDEN + p * 4];
            atomicAdd(sp + 0, h.x);
            atomicAdd(sp + 1, h.y);
            atomicAdd(sp + 2, h.z);
            atomicAdd(sp + 3, h.w);
            if (p == 0) atomicAdd(&scnt[g], 1.f);
        }
    }
    __syncthreads();
    // flush block partials (device-scope atomics; memory-side on gfx950)
    for (int i = t; i < NUM_GRAPHS * HIDDEN; i += 256) {
        float v = ssum[i];
        if (v != 0.f) atomicAdd(&sums[i], v);
    }
    if (t < NUM_GRAPHS) {
        float v = scnt[t];
        if (v != 0.f) atomicAdd(&counts[t], v);
    }
    __syncthreads();   // drains this block's vmem before signaling done
    if (t == 0) sdone = atomicAdd(done, 1u);
    __syncthreads();
    if (sdone == POOL_BLOCKS - 1) {
        // last block: all other blocks' flushes complete -> FC head
        __threadfence();
        for (int i = t; i < NUM_GRAPHS * NUM_CLS; i += 256) {
            int g = i / NUM_CLS, c = i % NUM_CLS;
            float inv = 1.0f / fmaxf(counts[g], 1.0f);
            float acc = bfc[c];
            #pragma unroll
            for (int kk = 0; kk < HIDDEN; ++kk)
                acc += (sums[g * HIDDEN + kk] * inv) * Wfc[kk * NUM_CLS + c];
            out[i] = acc;
        }
    }
}

extern "C" void kernel_launch(void* const* d_in, const int* in_sizes, int n_in,
                              void* d_out, int out_size, void* d_ws, size_t ws_size,
                              hipStream_t stream) {
    const float* x    = (const float*)d_in[0];
    const int*   ei   = (const int*)d_in[1];   // [2, E] (src row then dst row)
    const int*   batch= (const int*)d_in[2];
    const float* W1   = (const float*)d_in[3];
    const float* b1   = (const float*)d_in[4];
    const float* W2   = (const float*)d_in[5];
    const float* b2   = (const float*)d_in[6];
    const float* Wfc  = (const float*)d_in[7];
    const float* bfc  = (const float*)d_in[8];
    float* out = (float*)d_out;

    const size_t NB = (size_t)N_NODES * HIDDEN * sizeof(float);   // 6.4 MB
    char* ws = (char*)d_ws;
    size_t off = 0;
    float* A = (float*)(ws + off); off += NB;
    float* B = (float*)(ws + off); off += NB;
    // zero-area (contiguous): gcur | sums | counts | done
    int*      gcur   = (int*)(ws + off);      off += (size_t)NBUCK * sizeof(int);
    float*    sums   = (float*)(ws + off);    off += (size_t)NUM_GRAPHS * HIDDEN * sizeof(float);
    float*    counts = (float*)(ws + off);    off += (size_t)NUM_GRAPHS * sizeof(float);
    unsigned* done   = (unsigned*)(ws + off); off += 16;
    const int nz = NBUCK + NUM_GRAPHS * HIDDEN + NUM_GRAPHS + 1;
    int* row    = (int*)(ws + off); off += (size_t)N_NODES * sizeof(int);
    int* deg    = (int*)(ws + off); off += (size_t)N_NODES * sizeof(int);
    off = (off + 15) & ~(size_t)15;
    unsigned* packed = (unsigned*)(ws + off); off += (size_t)NBUCK * CAP * sizeof(unsigned);
    int* srcidx      = (int*)(ws + off);      off += (size_t)NBUCK * CAP * sizeof(int);

    const int gridMM1 = (N_NODES + MM1_ROWS - 1) / MM1_ROWS;
    const int gridG1  = (N_NODES + 63) / 64;
    const int poolChunk = (N_NODES + POOL_BLOCKS - 1) / POOL_BLOCKS;

    // K1: mm1 (+1 block zeroing gcur/sums/counts/done)
    k_mm1z<<<gridMM1 + 1, 256, 0, stream>>>(x, W1, A, gcur, nz, N_NODES, gridMM1);
    // K2: hist + capacity-alloc + place
    k_place2<<<NBLK, 256, 0, stream>>>(ei, gcur, packed);
    // K3: per-bucket CSR finalize (gapped srcidx, row+deg)
    k_build2<<<NBUCK, 256, 0, stream>>>(packed, gcur, row, deg, srcidx);
    // K4: layer 1+2 fused: B = relu(A + gather(A) + b1) @ W2
    k_g1f<<<gridG1, 256, 0, stream>>>(row, deg, srcidx, A, b1, W2, B, N_NODES);
    // K5: pool(relu(B + gather(B) + b2)) -> sums/counts ; last block does FC
    k_g2p<<<POOL_BLOCKS, 256, 0, stream>>>(row, deg, srcidx, B, b2, batch, sums, counts,
                                           done, Wfc, bfc, out, N_NODES, poolChunk);
}